// Round 1
// baseline (807.245 us; speedup 1.0000x reference)
//
#include <hip/hip_runtime.h>
#include <math.h>

#define BB 16
#define SS 64
#define NN 128
#define FF 16
#define HH 64
#define EE 1024
#define ET 1152   // EE + NN self-loops
#define LLAYERS 2
#define XPAD 65   // padded LDS row stride for xl/xr (bank = (s+h)%32)

__device__ __forceinline__ float readlane_f(float v, int k) {
  return __int_as_float(__builtin_amdgcn_readlane(__float_as_int(v), k));
}
// monotonic float<->uint mapping for atomicMax-based float max
__device__ __forceinline__ unsigned flipf(float f) {
  unsigned u = __float_as_uint(f);
  unsigned mask = (u & 0x80000000u) ? 0xFFFFFFFFu : 0x80000000u;
  return u ^ mask;
}
__device__ __forceinline__ float unflipf(unsigned u) {
  unsigned b = (u & 0x80000000u) ? (u ^ 0x80000000u) : ~u;
  return __uint_as_float(b);
}
__device__ __forceinline__ float sigmoidf_(float x) { return 1.f / (1.f + expf(-x)); }

// ---------------- CSR setup (graph is identical for every (b,s)) -------------
__global__ void setup_csr_kernel(const int* __restrict__ ei,
                                 int* __restrict__ off,
                                 int* __restrict__ csrc,
                                 int* __restrict__ ctgt) {
  __shared__ int deg[NN], cur[NN], offs[NN + 1];
  int tid = threadIdx.x;
  if (tid < NN) deg[tid] = 0;
  __syncthreads();
  for (int e = tid; e < ET; e += 256) {
    int tg = (e < EE) ? ei[EE + e] : (e - EE);
    atomicAdd(&deg[tg], 1);
  }
  __syncthreads();
  if (tid == 0) {
    int s = 0;
    for (int i = 0; i < NN; ++i) { offs[i] = s; s += deg[i]; }
    offs[NN] = s;
  }
  __syncthreads();
  if (tid < NN) cur[tid] = offs[tid];
  if (tid <= NN) off[tid] = offs[tid];
  __syncthreads();
  for (int e = tid; e < ET; e += 256) {
    int sv, tg;
    if (e < EE) { sv = ei[e]; tg = ei[EE + e]; }
    else        { sv = e - EE; tg = e - EE; }
    int pos = atomicAdd(&cur[tg], 1);
    csrc[pos] = sv;
    ctgt[pos] = tg;
  }
}

// ---------------- input projection: h = x @ W^T + b --------------------------
__global__ __launch_bounds__(256) void input_proj_kernel(
    const float* __restrict__ x, const float* __restrict__ W,
    const float* __restrict__ bvec, float* __restrict__ h) {
  int lane = threadIdx.x & 63;
  int wid = threadIdx.x >> 6;
  float wreg[FF];
#pragma unroll
  for (int i = 0; i < FF / 4; ++i)
    *(float4*)&wreg[4 * i] = ((const float4*)(W + lane * FF))[i];
  float bias = bvec[lane];
  int row0 = __builtin_amdgcn_readfirstlane((blockIdx.x * 4 + wid) * 32);
#pragma unroll 2
  for (int r = 0; r < 32; ++r) {
    int row = row0 + r;
    const float* xr = x + row * FF;
    float acc = bias;
#pragma unroll
    for (int f = 0; f < FF; ++f) acc += xr[f] * wreg[f];
    h[row * HH + lane] = acc;
  }
}

// ---------------- GAT kernel A: xl = h@Wl^T+bl, xr = h@Wr^T+br ---------------
__global__ __launch_bounds__(256) void xlxr_kernel(
    const float* __restrict__ hin,
    const float* __restrict__ Wl, const float* __restrict__ bl,
    const float* __restrict__ Wr, const float* __restrict__ br,
    float* __restrict__ xl, float* __restrict__ xr) {
  int lane = threadIdx.x & 63;
  int wid = (int)threadIdx.x >> 6;              // 0..3
  const float* W  = (wid & 1) ? Wr : Wl;
  const float* bv = (wid & 1) ? br : bl;
  float* outp     = (wid & 1) ? xr : xl;
  float w[HH];
#pragma unroll
  for (int i = 0; i < HH / 4; ++i)
    *(float4*)&w[4 * i] = ((const float4*)(W + lane * HH))[i];
  float bias = bv[lane];
  int row0 = __builtin_amdgcn_readfirstlane(blockIdx.x * 64 + (wid >> 1) * 32);
#pragma unroll 2
  for (int r = 0; r < 32; ++r) {
    const float* hrow = hin + (size_t)(row0 + r) * HH;
    float a0 = bias, a1 = 0.f, a2 = 0.f, a3 = 0.f;
#pragma unroll
    for (int f = 0; f < HH; f += 4) {
      a0 += hrow[f + 0] * w[f + 0];
      a1 += hrow[f + 1] * w[f + 1];
      a2 += hrow[f + 2] * w[f + 2];
      a3 += hrow[f + 3] * w[f + 3];
    }
    outp[(size_t)(row0 + r) * HH + lane] = (a0 + a1) + (a2 + a3);
  }
}

// ---------------- GAT kernel B: edge logits + softmax + aggregate ------------
__global__ __launch_bounds__(256) void gat_edge_kernel(
    const float* __restrict__ xl_g, const float* __restrict__ xr_g,
    float* __restrict__ hout,
    const int* __restrict__ csr_off, const int* __restrict__ csr_src,
    const int* __restrict__ csr_tgt,
    const float* __restrict__ att, const float* __restrict__ bo) {
  __shared__ float xl_sh[NN * XPAD];   // 33.3 KB
  __shared__ float xr_sh[NN * XPAD];   // 33.3 KB
  __shared__ float p_sh[ET];
  __shared__ int st_sh[ET];
  __shared__ unsigned m_sh[NN];
  int tid = threadIdx.x, lane = tid & 63, wid = tid >> 6;
  int base = blockIdx.x * (NN * HH);

  // stage xl/xr with padded stride
#pragma unroll 1
  for (int i = tid * 4; i < NN * HH; i += 256 * 4) {
    int row = i >> 6, h = i & 63;
    float4 vl = *(const float4*)(xl_g + base + i);
    float4 vr = *(const float4*)(xr_g + base + i);
    float* dl = xl_sh + row * XPAD + h;
    float* dr = xr_sh + row * XPAD + h;
    dl[0] = vl.x; dl[1] = vl.y; dl[2] = vl.z; dl[3] = vl.w;
    dr[0] = vr.x; dr[1] = vr.y; dr[2] = vr.z; dr[3] = vr.w;
  }
  for (int i = tid; i < ET; i += 256)
    st_sh[i] = csr_src[i] | (csr_tgt[i] << 16);
  if (tid < NN) m_sh[tid] = 0u;
  __syncthreads();

  // pass 1: thread-per-edge attention logit + segment max
#pragma unroll 1
  for (int e = tid; e < ET; e += 256) {
    int st = st_sh[e];
    int s = st & 0xffff, tg = st >> 16;
    const float* xlr = xl_sh + s * XPAD;
    const float* xrr = xr_sh + tg * XPAD;
    float a0 = 0.f, a1 = 0.f, a2 = 0.f, a3 = 0.f;
#pragma unroll
    for (int h = 0; h < HH; h += 4) {
      float v0 = xlr[h + 0] + xrr[h + 0]; v0 = (v0 > 0.f) ? v0 : 0.2f * v0;
      float v1 = xlr[h + 1] + xrr[h + 1]; v1 = (v1 > 0.f) ? v1 : 0.2f * v1;
      float v2 = xlr[h + 2] + xrr[h + 2]; v2 = (v2 > 0.f) ? v2 : 0.2f * v2;
      float v3 = xlr[h + 3] + xrr[h + 3]; v3 = (v3 > 0.f) ? v3 : 0.2f * v3;
      a0 += v0 * att[h + 0];
      a1 += v1 * att[h + 1];
      a2 += v2 * att[h + 2];
      a3 += v3 * att[h + 3];
    }
    float a = (a0 + a1) + (a2 + a3);
    p_sh[e] = a;
    atomicMax(&m_sh[tg], flipf(a));
  }
  __syncthreads();

  // pass 2: stabilized exp
  for (int e = tid; e < ET; e += 256) {
    int tg = st_sh[e] >> 16;
    p_sh[e] = expf(p_sh[e] - unflipf(m_sh[tg]));
  }
  __syncthreads();

  // gather: wave per target node, CSR-contiguous edge segment
  float bo_l = bo[lane];
#pragma unroll 1
  for (int n = wid; n < NN; n += 4) {
    int o0 = __builtin_amdgcn_readfirstlane(csr_off[n]);
    int o1 = __builtin_amdgcn_readfirstlane(csr_off[n + 1]);
    float acc = 0.f, z = 0.f;
    for (int i = o0; i < o1; ++i) {
      float p = p_sh[i];
      int s = st_sh[i] & 0xffff;
      acc += p * xl_sh[s * XPAD + lane];
      z += p;
    }
    float o = acc / z + bo_l;
    hout[base + n * HH + lane] = fmaxf(o, 0.f);
  }
}

// ---------------- fallback fused GAT (used if ws too small) ------------------
__device__ __forceinline__ void gemm_half(
    const float* __restrict__ hin, int base,
    const float* __restrict__ W, const float* __restrict__ bvec,
    float* __restrict__ out_sh, int half, int lane) {
  float wreg[HH];
#pragma unroll
  for (int i = 0; i < HH / 4; ++i)
    *(float4*)&wreg[4 * i] = ((const float4*)(W + lane * HH))[i];
  float bias = bvec[lane];
  int n0 = __builtin_amdgcn_readfirstlane(half * 64);
#pragma unroll 1
  for (int nd = 0; nd < 64; ++nd) {
    int node = n0 + nd;
    const float* hrow = hin + base + node * HH;
    float a0 = bias, a1 = 0.f, a2 = 0.f, a3 = 0.f;
#pragma unroll
    for (int f = 0; f < HH; f += 4) {
      a0 += hrow[f + 0] * wreg[f + 0];
      a1 += hrow[f + 1] * wreg[f + 1];
      a2 += hrow[f + 2] * wreg[f + 2];
      a3 += hrow[f + 3] * wreg[f + 3];
    }
    out_sh[node * HH + lane] = (a0 + a1) + (a2 + a3);
  }
}

__global__ __launch_bounds__(256) void gat_fused_kernel(
    const float* __restrict__ hin, float* __restrict__ hout,
    const int* __restrict__ csr_off, const int* __restrict__ csr_src,
    const int* __restrict__ csr_tgt,
    const float* __restrict__ Wl, const float* __restrict__ bl,
    const float* __restrict__ Wr, const float* __restrict__ br,
    const float* __restrict__ att, const float* __restrict__ bo) {
  __shared__ float xl_sh[NN * HH];
  __shared__ float xr_sh[NN * HH];
  __shared__ float p_sh[ET];
  __shared__ int st_sh[ET];
  __shared__ unsigned m_sh[NN];
  int tid = threadIdx.x, lane = tid & 63, wid = tid >> 6;
  int base = blockIdx.x * (NN * HH);

  for (int i = tid; i < ET; i += 256)
    st_sh[i] = csr_src[i] | (csr_tgt[i] << 16);
  if (tid < NN) m_sh[tid] = 0u;

  if (wid < 2) gemm_half(hin, base, Wl, bl, xl_sh, wid & 1, lane);
  else         gemm_half(hin, base, Wr, br, xr_sh, wid & 1, lane);

  float att_l = att[lane];
  float bo_l = bo[lane];
  __syncthreads();

#pragma unroll 1
  for (int e = wid; e < ET; e += 4) {
    int st = st_sh[e];
    int s = st & 0xffff, tg = st >> 16;
    float v = xl_sh[s * HH + lane] + xr_sh[tg * HH + lane];
    v = (v > 0.f) ? v : 0.2f * v;
    float prod = v * att_l;
#pragma unroll
    for (int mm = 32; mm; mm >>= 1) prod += __shfl_xor(prod, mm);
    if (lane == 0) {
      p_sh[e] = prod;
      atomicMax(&m_sh[tg], flipf(prod));
    }
  }
  __syncthreads();

  for (int e = tid; e < ET; e += 256) {
    int tg = st_sh[e] >> 16;
    p_sh[e] = expf(p_sh[e] - unflipf(m_sh[tg]));
  }
  __syncthreads();

#pragma unroll 1
  for (int n = wid; n < NN; n += 4) {
    int o0 = csr_off[n], o1 = csr_off[n + 1];
    float acc = 0.f, z = 0.f;
    for (int i = o0; i < o1; ++i) {
      float p = p_sh[i];
      int s = st_sh[i] & 0xffff;
      acc += p * xl_sh[s * HH + lane];
      z += p;
    }
    float o = acc / z + bo_l;
    hout[base + n * HH + lane] = fmaxf(o, 0.f);
  }
}

// ---------------- GRU: fused per-sequence, gate-split waves ------------------
// 3 waves per block, one sequence per block.
// Phase 1: wave g computes gi[t][g][j] = x_t @ Wih[g]^T + bih[g] for ALL 64
//   timesteps into LDS (48 KB). Each lane holds ONE 64-float Wih row -> no
//   spills (the old design's wt[3][64]=192 floats vs 112 reported VGPRs was
//   AGPR/scratch-bouncing every step). x-row reads are wave-uniform (scalar
//   loads), no readlane, no per-step sync.
// Phase 2: recurrence. Wave g computes gh_g = h @ Whh[g]^T + bhh[g] using
//   wave-uniform float4 LDS broadcasts of h (16x ds_read_b128, conflict-free)
//   -> no v_readlane SGPR-hazard chains. 768 B exchange buffer; wave 0
//   finishes gates + h update. 2 barriers/step; LDS 50 KB -> 3 blocks/CU so
//   other blocks' phase-1/phase-2 work fills barrier stalls.
// Heads stay fused on wave 0.
__global__ __launch_bounds__(192, 4) void gru_fused_kernel(
    const float* __restrict__ hbuf,
    const float* __restrict__ Wih, const float* __restrict__ Whh,
    const float* __restrict__ bih, const float* __restrict__ bhh,
    const float* __restrict__ oW1, const float* __restrict__ ob1,
    const float* __restrict__ oW2, const float* __restrict__ ob2,
    const float* __restrict__ dW1, const float* __restrict__ db1,
    const float* __restrict__ dW2, const float* __restrict__ db2,
    float* __restrict__ out) {
  __shared__ float gi_sh[SS * 3 * HH];   // 48 KB  [t][gate][j]
  __shared__ float exch[3 * HH];         // per-step gate exchange
  __shared__ float hsh[HH];              // current h (broadcast source)

  int lane = threadIdx.x & 63;
  int g = (int)threadIdx.x >> 6;         // gate wave 0..2
  int seq = blockIdx.x;                  // b*N + n
  int b = seq >> 7, n = seq & (NN - 1);
  const float* xbase = hbuf + ((size_t)b * SS * NN + (size_t)n) * HH;

  // ---- phase 1: gi for all timesteps ----
  {
    float w[HH];
    const float4* wsrc = (const float4*)(Wih + (size_t)(g * 64 + lane) * HH);
#pragma unroll
    for (int i = 0; i < HH / 4; ++i) *(float4*)&w[4 * i] = wsrc[i];
    float bias = bih[g * 64 + lane];
    if (g == 0) hsh[lane] = 0.f;
#pragma unroll 2
    for (int t = 0; t < SS; ++t) {
      const float* xr = xbase + (size_t)t * NN * HH;   // wave-uniform address
      float a0 = bias, a1 = 0.f, a2 = 0.f, a3 = 0.f;
#pragma unroll
      for (int k = 0; k < HH; k += 4) {
        float4 xb = *(const float4*)(xr + k);          // scalar/broadcast load
        a0 += xb.x * w[k + 0];
        a1 += xb.y * w[k + 1];
        a2 += xb.z * w[k + 2];
        a3 += xb.w * w[k + 3];
      }
      gi_sh[(t * 3 + g) * HH + lane] = (a0 + a1) + (a2 + a3);
    }
  }

  // ---- phase 2: recurrence ----
  float whh[HH];
  {
    const float4* wsrc = (const float4*)(Whh + (size_t)(g * 64 + lane) * HH);
#pragma unroll
    for (int i = 0; i < HH / 4; ++i) *(float4*)&whh[4 * i] = wsrc[i];
  }
  float bhg = bhh[g * 64 + lane];
  float hj = 0.f;                        // wave 0's copy of h[lane]
  __syncthreads();                       // gi + hsh=0 visible

#pragma unroll 1
  for (int t = 0; t < SS; ++t) {
    float gi_g = gi_sh[(t * 3 + g) * HH + lane];
    float a0 = bhg, a1 = 0.f, a2 = 0.f, a3 = 0.f;
#pragma unroll
    for (int k = 0; k < HH; k += 4) {
      float4 hb = *(const float4*)(hsh + k);           // ds_read_b128 broadcast
      a0 += hb.x * whh[k + 0];
      a1 += hb.y * whh[k + 1];
      a2 += hb.z * whh[k + 2];
      a3 += hb.w * whh[k + 3];
    }
    float gh = (a0 + a1) + (a2 + a3);
    // r,z gates carry gi+gh; n gate must keep gh separate (n = tanh(gi_n + r*gh_n))
    exch[g * HH + lane] = (g < 2) ? (gi_g + gh) : gh;
    __syncthreads();
    if (g == 0) {
      float sr  = exch[lane];
      float sz  = exch[HH + lane];
      float hn  = exch[2 * HH + lane];
      float gin = gi_sh[(t * 3 + 2) * HH + lane];
      float r = sigmoidf_(sr);
      float z = sigmoidf_(sz);
      float nn_ = tanhf(gin + r * hn);
      hj = (1.f - z) * nn_ + z * hj;
      hsh[lane] = hj;
    }
    __syncthreads();
  }

  // ---- fused heads on wave 0: lanes 0..31 order head, 32..63 demand head ----
  if (g == 0) {
    int half = lane >> 5, jp = lane & 31;
    const float* W1 = half ? dW1 : oW1;
    const float* b1 = half ? db1 : ob1;
    const float* W2 = half ? dW2 : oW2;
    const float* b2 = half ? db2 : ob2;
    float wv[HH];
#pragma unroll
    for (int i = 0; i < HH / 4; ++i)
      *(float4*)&wv[4 * i] = ((const float4*)(W1 + jp * HH))[i];
    float acc = b1[jp];
#pragma unroll
    for (int k = 0; k < HH; k += 4) {
      float4 hb = *(const float4*)(hsh + k);   // wave-uniform broadcast
      acc += hb.x * wv[k + 0];
      acc += hb.y * wv[k + 1];
      acc += hb.z * wv[k + 2];
      acc += hb.w * wv[k + 3];
    }
    float val = fmaxf(acc, 0.f) * W2[jp];
    val += __shfl_down(val, 16, 32);
    val += __shfl_down(val, 8, 32);
    val += __shfl_down(val, 4, 32);
    val += __shfl_down(val, 2, 32);
    val += __shfl_down(val, 1, 32);
    if (jp == 0) out[half * (BB * NN) + seq] = val + b2[0];
  }
}

// ---------------- launch -----------------------------------------------------
extern "C" void kernel_launch(void* const* d_in, const int* in_sizes, int n_in,
                              void* d_out, int out_size, void* d_ws, size_t ws_size,
                              hipStream_t stream) {
  const float* x       = (const float*)d_in[0];
  const int*   ei      = (const int*)d_in[1];
  const float* in_W    = (const float*)d_in[2];
  const float* in_b    = (const float*)d_in[3];
  const float* gat_Wl  = (const float*)d_in[4];
  const float* gat_bl  = (const float*)d_in[5];
  const float* gat_Wr  = (const float*)d_in[6];
  const float* gat_br  = (const float*)d_in[7];
  const float* gat_att = (const float*)d_in[8];
  const float* gat_bias= (const float*)d_in[9];
  const float* gru_Wih = (const float*)d_in[10];
  const float* gru_Whh = (const float*)d_in[11];
  const float* gru_bih = (const float*)d_in[12];
  const float* gru_bhh = (const float*)d_in[13];
  const float* oh_W1   = (const float*)d_in[14];
  const float* oh_b1   = (const float*)d_in[15];
  const float* oh_W2   = (const float*)d_in[16];
  const float* oh_b2   = (const float*)d_in[17];
  const float* dh_W1   = (const float*)d_in[18];
  const float* dh_b1   = (const float*)d_in[19];
  const float* dh_W2   = (const float*)d_in[20];
  const float* dh_b2   = (const float*)d_in[21];
  float* out = (float*)d_out;

  char* ws = (char*)d_ws;
  size_t hfloats = (size_t)BB * SS * NN * HH;           // 8.39M floats
  float* hbuf = (float*)ws;
  size_t off_csr = hfloats * sizeof(float);
  size_t off_buf = off_csr + (160 + 2 * ET) * sizeof(int);
  off_buf = (off_buf + 255) & ~(size_t)255;             // 256B align
  int* csr_off = (int*)(ws + off_csr);
  int* csr_src = csr_off + 160;
  int* csr_tgt = csr_src + ET;
  float* xlbuf = (float*)(ws + off_buf);
  float* xrbuf = xlbuf + hfloats;
  size_t need_gat = off_buf + 2 * hfloats * sizeof(float);
  bool big_gat = (ws_size >= need_gat);

  setup_csr_kernel<<<1, 256, 0, stream>>>(ei, csr_off, csr_src, csr_tgt);
  input_proj_kernel<<<(BB * SS * NN) / (4 * 32), 256, 0, stream>>>(x, in_W, in_b, hbuf);
  for (int l = 0; l < LLAYERS; ++l) {
    if (big_gat) {
      xlxr_kernel<<<(BB * SS * NN) / 64, 256, 0, stream>>>(
          hbuf, gat_Wl + l * HH * HH, gat_bl + l * HH,
          gat_Wr + l * HH * HH, gat_br + l * HH, xlbuf, xrbuf);
      gat_edge_kernel<<<BB * SS, 256, 0, stream>>>(
          xlbuf, xrbuf, hbuf, csr_off, csr_src, csr_tgt,
          gat_att + l * HH, gat_bias + l * HH);
    } else {
      gat_fused_kernel<<<BB * SS, 256, 0, stream>>>(
          hbuf, hbuf, csr_off, csr_src, csr_tgt,
          gat_Wl + l * HH * HH, gat_bl + l * HH,
          gat_Wr + l * HH * HH, gat_br + l * HH,
          gat_att + l * HH, gat_bias + l * HH);
    }
  }
  gru_fused_kernel<<<BB * NN, 192, 0, stream>>>(
      hbuf, gru_Wih, gru_Whh, gru_bih, gru_bhh,
      oh_W1, oh_b1, oh_W2, oh_b2, dh_W1, dh_b1, dh_W2, dh_b2, out);
}

// Round 2
// 781.346 us; speedup vs baseline: 1.0331x; 1.0331x over previous
//
#include <hip/hip_runtime.h>
#include <math.h>

#define BB 16
#define SS 64
#define NN 128
#define FF 16
#define HH 64
#define EE 1024
#define ET 1152   // EE + NN self-loops
#define LLAYERS 2
#define XPAD 65   // padded LDS row stride for xl/xr (bank = (s+h)%32)

__device__ __forceinline__ float readlane_f(float v, int k) {
  return __int_as_float(__builtin_amdgcn_readlane(__float_as_int(v), k));
}
// monotonic float<->uint mapping for atomicMax-based float max
__device__ __forceinline__ unsigned flipf(float f) {
  unsigned u = __float_as_uint(f);
  unsigned mask = (u & 0x80000000u) ? 0xFFFFFFFFu : 0x80000000u;
  return u ^ mask;
}
__device__ __forceinline__ float unflipf(unsigned u) {
  unsigned b = (u & 0x80000000u) ? (u ^ 0x80000000u) : ~u;
  return __uint_as_float(b);
}
__device__ __forceinline__ float sigmoidf_(float x) { return 1.f / (1.f + expf(-x)); }

// ---------------- CSR setup (graph is identical for every (b,s)) -------------
__global__ void setup_csr_kernel(const int* __restrict__ ei,
                                 int* __restrict__ off,
                                 int* __restrict__ csrc,
                                 int* __restrict__ ctgt) {
  __shared__ int deg[NN], cur[NN], offs[NN + 1];
  int tid = threadIdx.x;
  if (tid < NN) deg[tid] = 0;
  __syncthreads();
  for (int e = tid; e < ET; e += 256) {
    int tg = (e < EE) ? ei[EE + e] : (e - EE);
    atomicAdd(&deg[tg], 1);
  }
  __syncthreads();
  if (tid == 0) {
    int s = 0;
    for (int i = 0; i < NN; ++i) { offs[i] = s; s += deg[i]; }
    offs[NN] = s;
  }
  __syncthreads();
  if (tid < NN) cur[tid] = offs[tid];
  if (tid <= NN) off[tid] = offs[tid];
  __syncthreads();
  for (int e = tid; e < ET; e += 256) {
    int sv, tg;
    if (e < EE) { sv = ei[e]; tg = ei[EE + e]; }
    else        { sv = e - EE; tg = e - EE; }
    int pos = atomicAdd(&cur[tg], 1);
    csrc[pos] = sv;
    ctgt[pos] = tg;
  }
}

// ---------------- input projection: h = x @ W^T + b --------------------------
__global__ __launch_bounds__(256) void input_proj_kernel(
    const float* __restrict__ x, const float* __restrict__ W,
    const float* __restrict__ bvec, float* __restrict__ h) {
  int lane = threadIdx.x & 63;
  int wid = threadIdx.x >> 6;
  float wreg[FF];
#pragma unroll
  for (int i = 0; i < FF / 4; ++i)
    *(float4*)&wreg[4 * i] = ((const float4*)(W + lane * FF))[i];
  float bias = bvec[lane];
  int row0 = __builtin_amdgcn_readfirstlane((blockIdx.x * 4 + wid) * 32);
#pragma unroll 2
  for (int r = 0; r < 32; ++r) {
    int row = row0 + r;
    const float* xr = x + row * FF;
    float acc = bias;
#pragma unroll
    for (int f = 0; f < FF; ++f) acc += xr[f] * wreg[f];
    h[row * HH + lane] = acc;
  }
}

// ---------------- GAT kernel A: xl = h@Wl^T+bl, xr = h@Wr^T+br ---------------
__global__ __launch_bounds__(256) void xlxr_kernel(
    const float* __restrict__ hin,
    const float* __restrict__ Wl, const float* __restrict__ bl,
    const float* __restrict__ Wr, const float* __restrict__ br,
    float* __restrict__ xl, float* __restrict__ xr) {
  int lane = threadIdx.x & 63;
  int wid = (int)threadIdx.x >> 6;              // 0..3
  const float* W  = (wid & 1) ? Wr : Wl;
  const float* bv = (wid & 1) ? br : bl;
  float* outp     = (wid & 1) ? xr : xl;
  float w[HH];
#pragma unroll
  for (int i = 0; i < HH / 4; ++i)
    *(float4*)&w[4 * i] = ((const float4*)(W + lane * HH))[i];
  float bias = bv[lane];
  int row0 = __builtin_amdgcn_readfirstlane(blockIdx.x * 64 + (wid >> 1) * 32);
#pragma unroll 2
  for (int r = 0; r < 32; ++r) {
    const float* hrow = hin + (size_t)(row0 + r) * HH;
    float a0 = bias, a1 = 0.f, a2 = 0.f, a3 = 0.f;
#pragma unroll
    for (int f = 0; f < HH; f += 4) {
      a0 += hrow[f + 0] * w[f + 0];
      a1 += hrow[f + 1] * w[f + 1];
      a2 += hrow[f + 2] * w[f + 2];
      a3 += hrow[f + 3] * w[f + 3];
    }
    outp[(size_t)(row0 + r) * HH + lane] = (a0 + a1) + (a2 + a3);
  }
}

// ---------------- GAT kernel B: edge logits + softmax + aggregate ------------
__global__ __launch_bounds__(256) void gat_edge_kernel(
    const float* __restrict__ xl_g, const float* __restrict__ xr_g,
    float* __restrict__ hout,
    const int* __restrict__ csr_off, const int* __restrict__ csr_src,
    const int* __restrict__ csr_tgt,
    const float* __restrict__ att, const float* __restrict__ bo) {
  __shared__ float xl_sh[NN * XPAD];   // 33.3 KB
  __shared__ float xr_sh[NN * XPAD];   // 33.3 KB
  __shared__ float p_sh[ET];
  __shared__ int st_sh[ET];
  __shared__ unsigned m_sh[NN];
  int tid = threadIdx.x, lane = tid & 63, wid = tid >> 6;
  int base = blockIdx.x * (NN * HH);

  // stage xl/xr with padded stride
#pragma unroll 1
  for (int i = tid * 4; i < NN * HH; i += 256 * 4) {
    int row = i >> 6, h = i & 63;
    float4 vl = *(const float4*)(xl_g + base + i);
    float4 vr = *(const float4*)(xr_g + base + i);
    float* dl = xl_sh + row * XPAD + h;
    float* dr = xr_sh + row * XPAD + h;
    dl[0] = vl.x; dl[1] = vl.y; dl[2] = vl.z; dl[3] = vl.w;
    dr[0] = vr.x; dr[1] = vr.y; dr[2] = vr.z; dr[3] = vr.w;
  }
  for (int i = tid; i < ET; i += 256)
    st_sh[i] = csr_src[i] | (csr_tgt[i] << 16);
  if (tid < NN) m_sh[tid] = 0u;
  __syncthreads();

  // pass 1: thread-per-edge attention logit + segment max
#pragma unroll 1
  for (int e = tid; e < ET; e += 256) {
    int st = st_sh[e];
    int s = st & 0xffff, tg = st >> 16;
    const float* xlr = xl_sh + s * XPAD;
    const float* xrr = xr_sh + tg * XPAD;
    float a0 = 0.f, a1 = 0.f, a2 = 0.f, a3 = 0.f;
#pragma unroll
    for (int h = 0; h < HH; h += 4) {
      float v0 = xlr[h + 0] + xrr[h + 0]; v0 = (v0 > 0.f) ? v0 : 0.2f * v0;
      float v1 = xlr[h + 1] + xrr[h + 1]; v1 = (v1 > 0.f) ? v1 : 0.2f * v1;
      float v2 = xlr[h + 2] + xrr[h + 2]; v2 = (v2 > 0.f) ? v2 : 0.2f * v2;
      float v3 = xlr[h + 3] + xrr[h + 3]; v3 = (v3 > 0.f) ? v3 : 0.2f * v3;
      a0 += v0 * att[h + 0];
      a1 += v1 * att[h + 1];
      a2 += v2 * att[h + 2];
      a3 += v3 * att[h + 3];
    }
    float a = (a0 + a1) + (a2 + a3);
    p_sh[e] = a;
    atomicMax(&m_sh[tg], flipf(a));
  }
  __syncthreads();

  // pass 2: stabilized exp
  for (int e = tid; e < ET; e += 256) {
    int tg = st_sh[e] >> 16;
    p_sh[e] = expf(p_sh[e] - unflipf(m_sh[tg]));
  }
  __syncthreads();

  // gather: wave per target node, CSR-contiguous edge segment
  float bo_l = bo[lane];
#pragma unroll 1
  for (int n = wid; n < NN; n += 4) {
    int o0 = __builtin_amdgcn_readfirstlane(csr_off[n]);
    int o1 = __builtin_amdgcn_readfirstlane(csr_off[n + 1]);
    float acc = 0.f, z = 0.f;
    for (int i = o0; i < o1; ++i) {
      float p = p_sh[i];
      int s = st_sh[i] & 0xffff;
      acc += p * xl_sh[s * XPAD + lane];
      z += p;
    }
    float o = acc / z + bo_l;
    hout[base + n * HH + lane] = fmaxf(o, 0.f);
  }
}

// ---------------- fallback fused GAT (used if ws too small) ------------------
__device__ __forceinline__ void gemm_half(
    const float* __restrict__ hin, int base,
    const float* __restrict__ W, const float* __restrict__ bvec,
    float* __restrict__ out_sh, int half, int lane) {
  float wreg[HH];
#pragma unroll
  for (int i = 0; i < HH / 4; ++i)
    *(float4*)&wreg[4 * i] = ((const float4*)(W + lane * HH))[i];
  float bias = bvec[lane];
  int n0 = __builtin_amdgcn_readfirstlane(half * 64);
#pragma unroll 1
  for (int nd = 0; nd < 64; ++nd) {
    int node = n0 + nd;
    const float* hrow = hin + base + node * HH;
    float a0 = bias, a1 = 0.f, a2 = 0.f, a3 = 0.f;
#pragma unroll
    for (int f = 0; f < HH; f += 4) {
      a0 += hrow[f + 0] * wreg[f + 0];
      a1 += hrow[f + 1] * wreg[f + 1];
      a2 += hrow[f + 2] * wreg[f + 2];
      a3 += hrow[f + 3] * wreg[f + 3];
    }
    out_sh[node * HH + lane] = (a0 + a1) + (a2 + a3);
  }
}

__global__ __launch_bounds__(256) void gat_fused_kernel(
    const float* __restrict__ hin, float* __restrict__ hout,
    const int* __restrict__ csr_off, const int* __restrict__ csr_src,
    const int* __restrict__ csr_tgt,
    const float* __restrict__ Wl, const float* __restrict__ bl,
    const float* __restrict__ Wr, const float* __restrict__ br,
    const float* __restrict__ att, const float* __restrict__ bo) {
  __shared__ float xl_sh[NN * HH];
  __shared__ float xr_sh[NN * HH];
  __shared__ float p_sh[ET];
  __shared__ int st_sh[ET];
  __shared__ unsigned m_sh[NN];
  int tid = threadIdx.x, lane = tid & 63, wid = tid >> 6;
  int base = blockIdx.x * (NN * HH);

  for (int i = tid; i < ET; i += 256)
    st_sh[i] = csr_src[i] | (csr_tgt[i] << 16);
  if (tid < NN) m_sh[tid] = 0u;

  if (wid < 2) gemm_half(hin, base, Wl, bl, xl_sh, wid & 1, lane);
  else         gemm_half(hin, base, Wr, br, xr_sh, wid & 1, lane);

  float att_l = att[lane];
  float bo_l = bo[lane];
  __syncthreads();

#pragma unroll 1
  for (int e = wid; e < ET; e += 4) {
    int st = st_sh[e];
    int s = st & 0xffff, tg = st >> 16;
    float v = xl_sh[s * HH + lane] + xr_sh[tg * HH + lane];
    v = (v > 0.f) ? v : 0.2f * v;
    float prod = v * att_l;
#pragma unroll
    for (int mm = 32; mm; mm >>= 1) prod += __shfl_xor(prod, mm);
    if (lane == 0) {
      p_sh[e] = prod;
      atomicMax(&m_sh[tg], flipf(prod));
    }
  }
  __syncthreads();

  for (int e = tid; e < ET; e += 256) {
    int tg = st_sh[e] >> 16;
    p_sh[e] = expf(p_sh[e] - unflipf(m_sh[tg]));
  }
  __syncthreads();

#pragma unroll 1
  for (int n = wid; n < NN; n += 4) {
    int o0 = csr_off[n], o1 = csr_off[n + 1];
    float acc = 0.f, z = 0.f;
    for (int i = o0; i < o1; ++i) {
      float p = p_sh[i];
      int s = st_sh[i] & 0xffff;
      acc += p * xl_sh[s * HH + lane];
      z += p;
    }
    float o = acc / z + bo_l;
    hout[base + n * HH + lane] = fmaxf(o, 0.f);
  }
}

// ---------------- GRU: fused per-sequence, gate-split waves ------------------
// 3 waves per block, one sequence per block, wave g owns gate g.
// Phase 1: wave g computes gi[t][g][j] = x_t @ Wih[g]^T + bih[g] for ALL 64
//   timesteps into LDS (48 KB). One 64-float Wih row per lane -> no spills.
// Phase 2 (R2 restructure): every wave keeps a full redundant copy of h in
//   its lane register hj. The h[k] broadcast for the gh matvec is
//   v_readlane of the wave's OWN hj -> no LDS round trip, no broadcast
//   barrier. Each wave computes its gate's gh, publishes it to a
//   double-buffered exch[2][3][64], ONE barrier, then ALL waves redundantly
//   compute r/z/n + the h update (transcendentals run in parallel on 3
//   SIMDs instead of serially on wave 0). Double buffering makes the
//   single barrier race-free (write slot t&1, barrier, read slot t&1;
//   step t+1 writes the other slot).
__global__ __launch_bounds__(192, 3) void gru_fused_kernel(
    const float* __restrict__ hbuf,
    const float* __restrict__ Wih, const float* __restrict__ Whh,
    const float* __restrict__ bih, const float* __restrict__ bhh,
    const float* __restrict__ oW1, const float* __restrict__ ob1,
    const float* __restrict__ oW2, const float* __restrict__ ob2,
    const float* __restrict__ dW1, const float* __restrict__ db1,
    const float* __restrict__ dW2, const float* __restrict__ db2,
    float* __restrict__ out) {
  __shared__ float gi_sh[SS * 3 * HH];   // 48 KB  [t][gate][j]
  __shared__ float exch[2][3][HH];       // 1.5 KB double-buffered gh exchange

  int lane = threadIdx.x & 63;
  int g = (int)threadIdx.x >> 6;         // gate wave 0..2
  int seq = blockIdx.x;                  // b*N + n
  int b = seq >> 7, n = seq & (NN - 1);
  const float* xbase = hbuf + ((size_t)b * SS * NN + (size_t)n) * HH;

  // ---- phase 1: gi for all timesteps ----
  {
    float w[HH];
    const float4* wsrc = (const float4*)(Wih + (size_t)(g * 64 + lane) * HH);
#pragma unroll
    for (int i = 0; i < HH / 4; ++i) *(float4*)&w[4 * i] = wsrc[i];
    float bias = bih[g * 64 + lane];
#pragma unroll 2
    for (int t = 0; t < SS; ++t) {
      const float* xr = xbase + (size_t)t * NN * HH;   // wave-uniform address
      float a0 = bias, a1 = 0.f, a2 = 0.f, a3 = 0.f;
#pragma unroll
      for (int k = 0; k < HH; k += 4) {
        float4 xb = *(const float4*)(xr + k);          // scalar/broadcast load
        a0 += xb.x * w[k + 0];
        a1 += xb.y * w[k + 1];
        a2 += xb.z * w[k + 2];
        a3 += xb.w * w[k + 3];
      }
      gi_sh[(t * 3 + g) * HH + lane] = (a0 + a1) + (a2 + a3);
    }
  }

  // ---- phase 2: recurrence ----
  float whh[HH];
  {
    const float4* wsrc = (const float4*)(Whh + (size_t)(g * 64 + lane) * HH);
#pragma unroll
    for (int i = 0; i < HH / 4; ++i) *(float4*)&whh[4 * i] = wsrc[i];
  }
  float bhg = bhh[g * 64 + lane];
  float hj = 0.f;                        // this wave's copy of h[lane]
  __syncthreads();                       // gi_sh visible

#pragma unroll 1
  for (int t = 0; t < SS; ++t) {
    // gh_g[lane] = bhg + sum_k h[k] * whh[lane][k]; h[k] via readlane of
    // this wave's own hj (no LDS, no barrier on the broadcast)
    float a0 = bhg, a1 = 0.f, a2 = 0.f, a3 = 0.f;
#pragma unroll
    for (int k = 0; k < HH; k += 4) {
      a0 += readlane_f(hj, k + 0) * whh[k + 0];
      a1 += readlane_f(hj, k + 1) * whh[k + 1];
      a2 += readlane_f(hj, k + 2) * whh[k + 2];
      a3 += readlane_f(hj, k + 3) * whh[k + 3];
    }
    float gh = (a0 + a1) + (a2 + a3);
    int slot = t & 1;
    exch[slot][g][lane] = gh;
    __syncthreads();                     // the ONLY barrier per step
    float ghr = exch[slot][0][lane];
    float ghz = exch[slot][1][lane];
    float ghn = exch[slot][2][lane];
    float gir = gi_sh[(t * 3 + 0) * HH + lane];
    float giz = gi_sh[(t * 3 + 1) * HH + lane];
    float gin = gi_sh[(t * 3 + 2) * HH + lane];
    // all 3 waves redundantly finish the gates + h update (parallel
    // transcendentals; keeps full h register-resident in every wave)
    float r  = sigmoidf_(gir + ghr);
    float z  = sigmoidf_(giz + ghz);
    float nn_ = tanhf(gin + r * ghn);
    hj = (1.f - z) * nn_ + z * hj;
  }

  // ---- fused heads on wave 0: lanes 0..31 order head, 32..63 demand head ----
  if (g == 0) {
    int half = lane >> 5, jp = lane & 31;
    const float* W1 = half ? dW1 : oW1;
    const float* b1 = half ? db1 : ob1;
    const float* W2 = half ? dW2 : oW2;
    const float* b2 = half ? db2 : ob2;
    float wv[HH];
#pragma unroll
    for (int i = 0; i < HH / 4; ++i)
      *(float4*)&wv[4 * i] = ((const float4*)(W1 + jp * HH))[i];
    float acc = b1[jp];
#pragma unroll
    for (int k = 0; k < HH; ++k)
      acc += readlane_f(hj, k) * wv[k];  // broadcast from own h copy
    float val = fmaxf(acc, 0.f) * W2[jp];
    val += __shfl_down(val, 16, 32);
    val += __shfl_down(val, 8, 32);
    val += __shfl_down(val, 4, 32);
    val += __shfl_down(val, 2, 32);
    val += __shfl_down(val, 1, 32);
    if (jp == 0) out[half * (BB * NN) + seq] = val + b2[0];
  }
}

// ---------------- launch -----------------------------------------------------
extern "C" void kernel_launch(void* const* d_in, const int* in_sizes, int n_in,
                              void* d_out, int out_size, void* d_ws, size_t ws_size,
                              hipStream_t stream) {
  const float* x       = (const float*)d_in[0];
  const int*   ei      = (const int*)d_in[1];
  const float* in_W    = (const float*)d_in[2];
  const float* in_b    = (const float*)d_in[3];
  const float* gat_Wl  = (const float*)d_in[4];
  const float* gat_bl  = (const float*)d_in[5];
  const float* gat_Wr  = (const float*)d_in[6];
  const float* gat_br  = (const float*)d_in[7];
  const float* gat_att = (const float*)d_in[8];
  const float* gat_bias= (const float*)d_in[9];
  const float* gru_Wih = (const float*)d_in[10];
  const float* gru_Whh = (const float*)d_in[11];
  const float* gru_bih = (const float*)d_in[12];
  const float* gru_bhh = (const float*)d_in[13];
  const float* oh_W1   = (const float*)d_in[14];
  const float* oh_b1   = (const float*)d_in[15];
  const float* oh_W2   = (const float*)d_in[16];
  const float* oh_b2   = (const float*)d_in[17];
  const float* dh_W1   = (const float*)d_in[18];
  const float* dh_b1   = (const float*)d_in[19];
  const float* dh_W2   = (const float*)d_in[20];
  const float* dh_b2   = (const float*)d_in[21];
  float* out = (float*)d_out;

  char* ws = (char*)d_ws;
  size_t hfloats = (size_t)BB * SS * NN * HH;           // 8.39M floats
  float* hbuf = (float*)ws;
  size_t off_csr = hfloats * sizeof(float);
  size_t off_buf = off_csr + (160 + 2 * ET) * sizeof(int);
  off_buf = (off_buf + 255) & ~(size_t)255;             // 256B align
  int* csr_off = (int*)(ws + off_csr);
  int* csr_src = csr_off + 160;
  int* csr_tgt = csr_src + ET;
  float* xlbuf = (float*)(ws + off_buf);
  float* xrbuf = xlbuf + hfloats;
  size_t need_gat = off_buf + 2 * hfloats * sizeof(float);
  bool big_gat = (ws_size >= need_gat);

  setup_csr_kernel<<<1, 256, 0, stream>>>(ei, csr_off, csr_src, csr_tgt);
  input_proj_kernel<<<(BB * SS * NN) / (4 * 32), 256, 0, stream>>>(x, in_W, in_b, hbuf);
  for (int l = 0; l < LLAYERS; ++l) {
    if (big_gat) {
      xlxr_kernel<<<(BB * SS * NN) / 64, 256, 0, stream>>>(
          hbuf, gat_Wl + l * HH * HH, gat_bl + l * HH,
          gat_Wr + l * HH * HH, gat_br + l * HH, xlbuf, xrbuf);
      gat_edge_kernel<<<BB * SS, 256, 0, stream>>>(
          xlbuf, xrbuf, hbuf, csr_off, csr_src, csr_tgt,
          gat_att + l * HH, gat_bias + l * HH);
    } else {
      gat_fused_kernel<<<BB * SS, 256, 0, stream>>>(
          hbuf, hbuf, csr_off, csr_src, csr_tgt,
          gat_Wl + l * HH * HH, gat_bl + l * HH,
          gat_Wr + l * HH * HH, gat_br + l * HH,
          gat_att + l * HH, gat_bias + l * HH);
    }
  }
  gru_fused_kernel<<<BB * NN, 192, 0, stream>>>(
      hbuf, gru_Wih, gru_Whh, gru_bih, gru_bhh,
      oh_W1, oh_b1, oh_W2, oh_b2, dh_W1, dh_b1, dh_W2, dh_b2, out);
}

// Round 3
// 750.262 us; speedup vs baseline: 1.0760x; 1.0414x over previous
//
#include <hip/hip_runtime.h>
#include <math.h>

#define BB 16
#define SS 64
#define NN 128
#define FF 16
#define HH 64
#define EE 1024
#define ET 1152   // EE + NN self-loops
#define LLAYERS 2
#define XPAD 65   // padded LDS row stride for xl/xr (bank = (s+h)%32)
#define RT (BB * SS * NN)   // 131072 GRU input rows

__device__ __forceinline__ float readlane_f(float v, int k) {
  return __int_as_float(__builtin_amdgcn_readlane(__float_as_int(v), k));
}
// monotonic float<->uint mapping for atomicMax-based float max
__device__ __forceinline__ unsigned flipf(float f) {
  unsigned u = __float_as_uint(f);
  unsigned mask = (u & 0x80000000u) ? 0xFFFFFFFFu : 0x80000000u;
  return u ^ mask;
}
__device__ __forceinline__ float unflipf(unsigned u) {
  unsigned b = (u & 0x80000000u) ? (u ^ 0x80000000u) : ~u;
  return __uint_as_float(b);
}
__device__ __forceinline__ float sigmoidf_(float x) { return 1.f / (1.f + expf(-x)); }

// ---------------- CSR setup (graph is identical for every (b,s)) -------------
__global__ void setup_csr_kernel(const int* __restrict__ ei,
                                 int* __restrict__ off,
                                 int* __restrict__ csrc,
                                 int* __restrict__ ctgt) {
  __shared__ int deg[NN], cur[NN], offs[NN + 1];
  int tid = threadIdx.x;
  if (tid < NN) deg[tid] = 0;
  __syncthreads();
  for (int e = tid; e < ET; e += 256) {
    int tg = (e < EE) ? ei[EE + e] : (e - EE);
    atomicAdd(&deg[tg], 1);
  }
  __syncthreads();
  if (tid == 0) {
    int s = 0;
    for (int i = 0; i < NN; ++i) { offs[i] = s; s += deg[i]; }
    offs[NN] = s;
  }
  __syncthreads();
  if (tid < NN) cur[tid] = offs[tid];
  if (tid <= NN) off[tid] = offs[tid];
  __syncthreads();
  for (int e = tid; e < ET; e += 256) {
    int sv, tg;
    if (e < EE) { sv = ei[e]; tg = ei[EE + e]; }
    else        { sv = e - EE; tg = e - EE; }
    int pos = atomicAdd(&cur[tg], 1);
    csrc[pos] = sv;
    ctgt[pos] = tg;
  }
}

// ---------------- input projection: h = x @ W^T + b --------------------------
__global__ __launch_bounds__(256) void input_proj_kernel(
    const float* __restrict__ x, const float* __restrict__ W,
    const float* __restrict__ bvec, float* __restrict__ h) {
  int lane = threadIdx.x & 63;
  int wid = threadIdx.x >> 6;
  float wreg[FF];
#pragma unroll
  for (int i = 0; i < FF / 4; ++i)
    *(float4*)&wreg[4 * i] = ((const float4*)(W + lane * FF))[i];
  float bias = bvec[lane];
  int row0 = __builtin_amdgcn_readfirstlane((blockIdx.x * 4 + wid) * 32);
#pragma unroll 2
  for (int r = 0; r < 32; ++r) {
    int row = row0 + r;
    const float* xr = x + row * FF;
    float acc = bias;
#pragma unroll
    for (int f = 0; f < FF; ++f) acc += xr[f] * wreg[f];
    h[row * HH + lane] = acc;
  }
}

// ---------------- GAT kernel A: xl = h@Wl^T+bl, xr = h@Wr^T+br ---------------
__global__ __launch_bounds__(256) void xlxr_kernel(
    const float* __restrict__ hin,
    const float* __restrict__ Wl, const float* __restrict__ bl,
    const float* __restrict__ Wr, const float* __restrict__ br,
    float* __restrict__ xl, float* __restrict__ xr) {
  int lane = threadIdx.x & 63;
  int wid = (int)threadIdx.x >> 6;              // 0..3
  const float* W  = (wid & 1) ? Wr : Wl;
  const float* bv = (wid & 1) ? br : bl;
  float* outp     = (wid & 1) ? xr : xl;
  float w[HH];
#pragma unroll
  for (int i = 0; i < HH / 4; ++i)
    *(float4*)&w[4 * i] = ((const float4*)(W + lane * HH))[i];
  float bias = bv[lane];
  int row0 = __builtin_amdgcn_readfirstlane(blockIdx.x * 64 + (wid >> 1) * 32);
#pragma unroll 2
  for (int r = 0; r < 32; ++r) {
    const float* hrow = hin + (size_t)(row0 + r) * HH;
    float a0 = bias, a1 = 0.f, a2 = 0.f, a3 = 0.f;
#pragma unroll
    for (int f = 0; f < HH; f += 4) {
      a0 += hrow[f + 0] * w[f + 0];
      a1 += hrow[f + 1] * w[f + 1];
      a2 += hrow[f + 2] * w[f + 2];
      a3 += hrow[f + 3] * w[f + 3];
    }
    outp[(size_t)(row0 + r) * HH + lane] = (a0 + a1) + (a2 + a3);
  }
}

// ---------------- GAT kernel B: edge logits + softmax + aggregate ------------
__global__ __launch_bounds__(256) void gat_edge_kernel(
    const float* __restrict__ xl_g, const float* __restrict__ xr_g,
    float* __restrict__ hout,
    const int* __restrict__ csr_off, const int* __restrict__ csr_src,
    const int* __restrict__ csr_tgt,
    const float* __restrict__ att, const float* __restrict__ bo) {
  __shared__ float xl_sh[NN * XPAD];   // 33.3 KB
  __shared__ float xr_sh[NN * XPAD];   // 33.3 KB
  __shared__ float p_sh[ET];
  __shared__ int st_sh[ET];
  __shared__ unsigned m_sh[NN];
  int tid = threadIdx.x, lane = tid & 63, wid = tid >> 6;
  int base = blockIdx.x * (NN * HH);

  // stage xl/xr with padded stride
#pragma unroll 1
  for (int i = tid * 4; i < NN * HH; i += 256 * 4) {
    int row = i >> 6, h = i & 63;
    float4 vl = *(const float4*)(xl_g + base + i);
    float4 vr = *(const float4*)(xr_g + base + i);
    float* dl = xl_sh + row * XPAD + h;
    float* dr = xr_sh + row * XPAD + h;
    dl[0] = vl.x; dl[1] = vl.y; dl[2] = vl.z; dl[3] = vl.w;
    dr[0] = vr.x; dr[1] = vr.y; dr[2] = vr.z; dr[3] = vr.w;
  }
  for (int i = tid; i < ET; i += 256)
    st_sh[i] = csr_src[i] | (csr_tgt[i] << 16);
  if (tid < NN) m_sh[tid] = 0u;
  __syncthreads();

  // pass 1: thread-per-edge attention logit + segment max
#pragma unroll 1
  for (int e = tid; e < ET; e += 256) {
    int st = st_sh[e];
    int s = st & 0xffff, tg = st >> 16;
    const float* xlr = xl_sh + s * XPAD;
    const float* xrr = xr_sh + tg * XPAD;
    float a0 = 0.f, a1 = 0.f, a2 = 0.f, a3 = 0.f;
#pragma unroll
    for (int h = 0; h < HH; h += 4) {
      float v0 = xlr[h + 0] + xrr[h + 0]; v0 = (v0 > 0.f) ? v0 : 0.2f * v0;
      float v1 = xlr[h + 1] + xrr[h + 1]; v1 = (v1 > 0.f) ? v1 : 0.2f * v1;
      float v2 = xlr[h + 2] + xrr[h + 2]; v2 = (v2 > 0.f) ? v2 : 0.2f * v2;
      float v3 = xlr[h + 3] + xrr[h + 3]; v3 = (v3 > 0.f) ? v3 : 0.2f * v3;
      a0 += v0 * att[h + 0];
      a1 += v1 * att[h + 1];
      a2 += v2 * att[h + 2];
      a3 += v3 * att[h + 3];
    }
    float a = (a0 + a1) + (a2 + a3);
    p_sh[e] = a;
    atomicMax(&m_sh[tg], flipf(a));
  }
  __syncthreads();

  // pass 2: stabilized exp
  for (int e = tid; e < ET; e += 256) {
    int tg = st_sh[e] >> 16;
    p_sh[e] = expf(p_sh[e] - unflipf(m_sh[tg]));
  }
  __syncthreads();

  // gather: wave per target node, CSR-contiguous edge segment
  float bo_l = bo[lane];
#pragma unroll 1
  for (int n = wid; n < NN; n += 4) {
    int o0 = __builtin_amdgcn_readfirstlane(csr_off[n]);
    int o1 = __builtin_amdgcn_readfirstlane(csr_off[n + 1]);
    float acc = 0.f, z = 0.f;
    for (int i = o0; i < o1; ++i) {
      float p = p_sh[i];
      int s = st_sh[i] & 0xffff;
      acc += p * xl_sh[s * XPAD + lane];
      z += p;
    }
    float o = acc / z + bo_l;
    hout[base + n * HH + lane] = fmaxf(o, 0.f);
  }
}

// ---------------- fallback fused GAT (used if ws too small) ------------------
__device__ __forceinline__ void gemm_half(
    const float* __restrict__ hin, int base,
    const float* __restrict__ W, const float* __restrict__ bvec,
    float* __restrict__ out_sh, int half, int lane) {
  float wreg[HH];
#pragma unroll
  for (int i = 0; i < HH / 4; ++i)
    *(float4*)&wreg[4 * i] = ((const float4*)(W + lane * HH))[i];
  float bias = bvec[lane];
  int n0 = __builtin_amdgcn_readfirstlane(half * 64);
#pragma unroll 1
  for (int nd = 0; nd < 64; ++nd) {
    int node = n0 + nd;
    const float* hrow = hin + base + node * HH;
    float a0 = bias, a1 = 0.f, a2 = 0.f, a3 = 0.f;
#pragma unroll
    for (int f = 0; f < HH; f += 4) {
      a0 += hrow[f + 0] * wreg[f + 0];
      a1 += hrow[f + 1] * wreg[f + 1];
      a2 += hrow[f + 2] * wreg[f + 2];
      a3 += hrow[f + 3] * wreg[f + 3];
    }
    out_sh[node * HH + lane] = (a0 + a1) + (a2 + a3);
  }
}

__global__ __launch_bounds__(256) void gat_fused_kernel(
    const float* __restrict__ hin, float* __restrict__ hout,
    const int* __restrict__ csr_off, const int* __restrict__ csr_src,
    const int* __restrict__ csr_tgt,
    const float* __restrict__ Wl, const float* __restrict__ bl,
    const float* __restrict__ Wr, const float* __restrict__ br,
    const float* __restrict__ att, const float* __restrict__ bo) {
  __shared__ float xl_sh[NN * HH];
  __shared__ float xr_sh[NN * HH];
  __shared__ float p_sh[ET];
  __shared__ int st_sh[ET];
  __shared__ unsigned m_sh[NN];
  int tid = threadIdx.x, lane = tid & 63, wid = tid >> 6;
  int base = blockIdx.x * (NN * HH);

  for (int i = tid; i < ET; i += 256)
    st_sh[i] = csr_src[i] | (csr_tgt[i] << 16);
  if (tid < NN) m_sh[tid] = 0u;

  if (wid < 2) gemm_half(hin, base, Wl, bl, xl_sh, wid & 1, lane);
  else         gemm_half(hin, base, Wr, br, xr_sh, wid & 1, lane);

  float att_l = att[lane];
  float bo_l = bo[lane];
  __syncthreads();

#pragma unroll 1
  for (int e = wid; e < ET; e += 4) {
    int st = st_sh[e];
    int s = st & 0xffff, tg = st >> 16;
    float v = xl_sh[s * HH + lane] + xr_sh[tg * HH + lane];
    v = (v > 0.f) ? v : 0.2f * v;
    float prod = v * att_l;
#pragma unroll
    for (int mm = 32; mm; mm >>= 1) prod += __shfl_xor(prod, mm);
    if (lane == 0) {
      p_sh[e] = prod;
      atomicMax(&m_sh[tg], flipf(prod));
    }
  }
  __syncthreads();

  for (int e = tid; e < ET; e += 256) {
    int tg = st_sh[e] >> 16;
    p_sh[e] = expf(p_sh[e] - unflipf(m_sh[tg]));
  }
  __syncthreads();

#pragma unroll 1
  for (int n = wid; n < NN; n += 4) {
    int o0 = csr_off[n], o1 = csr_off[n + 1];
    float acc = 0.f, z = 0.f;
    for (int i = o0; i < o1; ++i) {
      float p = p_sh[i];
      int s = st_sh[i] & 0xffff;
      acc += p * xl_sh[s * HH + lane];
      z += p;
    }
    float o = acc / z + bo_l;
    hout[base + n * HH + lane] = fmaxf(o, 0.f);
  }
}

// ---------------- GRU stage A: gi = hbuf @ Wih^T + bih  (batched GEMM) -------
// No sequential dependency -> plain GEMM over all 131072 (b,t,n) rows.
// 3 waves per block, wave w owns gate w's 64 outputs (one Wih row per lane,
// register-resident). x rows are wave-uniform -> scalar-cached broadcasts.
__global__ __launch_bounds__(192) void gi_proj_kernel(
    const float* __restrict__ hin, const float* __restrict__ Wih,
    const float* __restrict__ bih, float* __restrict__ gi) {
  int lane = threadIdx.x & 63;
  int w = (int)threadIdx.x >> 6;               // gate 0..2
  float wreg[HH];
  const float4* wsrc = (const float4*)(Wih + (size_t)(w * 64 + lane) * HH);
#pragma unroll
  for (int i = 0; i < HH / 4; ++i) *(float4*)&wreg[4 * i] = wsrc[i];
  float bias = bih[w * 64 + lane];
  int row0 = __builtin_amdgcn_readfirstlane(blockIdx.x * 64);
#pragma unroll 2
  for (int r = 0; r < 64; ++r) {
    int row = row0 + r;
    const float* hrow = hin + (size_t)row * HH;
    float a0 = bias, a1 = 0.f, a2 = 0.f, a3 = 0.f;
#pragma unroll
    for (int f = 0; f < HH; f += 4) {
      a0 += hrow[f + 0] * wreg[f + 0];
      a1 += hrow[f + 1] * wreg[f + 1];
      a2 += hrow[f + 2] * wreg[f + 2];
      a3 += hrow[f + 3] * wreg[f + 3];
    }
    gi[(size_t)row * 192 + w * 64 + lane] = (a0 + a1) + (a2 + a3);
  }
}

// ---------------- GRU stage B: recurrence, one wave per sequence -------------
// 2048 blocks x 64 threads; zero barriers, zero LDS, zero inter-wave traffic.
// Lane j holds Whh rows {j, 64+j, 128+j} (192 floats; __launch_bounds__(64,2)
// -> 256-reg budget, fits without spill). h broadcast = v_readlane of the
// wave's own hj. gi streamed from global with depth-2 prefetch (2 iters
// ~1200 cyc cover > ~900 cyc HBM latency). 2 waves/SIMD * 4 SIMD * 256 CU =
// 2048 waves -> every sequence resident simultaneously, one round.
__global__ __launch_bounds__(64, 2) void gru_rec_kernel(
    const float* __restrict__ gi,
    const float* __restrict__ Whh, const float* __restrict__ bhh,
    const float* __restrict__ oW1, const float* __restrict__ ob1,
    const float* __restrict__ oW2, const float* __restrict__ ob2,
    const float* __restrict__ dW1, const float* __restrict__ db1,
    const float* __restrict__ dW2, const float* __restrict__ db2,
    float* __restrict__ out) {
  int lane = threadIdx.x;                      // 0..63
  int seq = blockIdx.x;                        // b*N + n
  int b = seq >> 7, n = seq & (NN - 1);

  float wr[HH], wz[HH], wn[HH];
  {
    const float4* s0 = (const float4*)(Whh + (size_t)(0 * 64 + lane) * HH);
    const float4* s1 = (const float4*)(Whh + (size_t)(1 * 64 + lane) * HH);
    const float4* s2 = (const float4*)(Whh + (size_t)(2 * 64 + lane) * HH);
#pragma unroll
    for (int i = 0; i < HH / 4; ++i) {
      *(float4*)&wr[4 * i] = s0[i];
      *(float4*)&wz[4 * i] = s1[i];
      *(float4*)&wn[4 * i] = s2[i];
    }
  }
  float br_ = bhh[lane], bz_ = bhh[64 + lane], bn_ = bhh[128 + lane];

  const float* gbase = gi + ((size_t)b * SS * NN + (size_t)n) * 192;  // +t*NN*192
  // depth-2 software pipeline on gi loads
  float gir = gbase[lane], giz = gbase[64 + lane], gin = gbase[128 + lane];
  const float* g1 = gbase + (size_t)NN * 192;
  float pir = g1[lane], piz = g1[64 + lane], pin = g1[128 + lane];
  float hj = 0.f;

#pragma unroll 1
  for (int t = 0; t < SS; ++t) {
    float qir = 0.f, qiz = 0.f, qin = 0.f;
    if (t + 2 < SS) {
      const float* g2 = gbase + (size_t)(t + 2) * NN * 192;
      qir = g2[lane]; qiz = g2[64 + lane]; qin = g2[128 + lane];
    }
    float ar0 = br_, ar1 = 0.f, az0 = bz_, az1 = 0.f, an0 = bn_, an1 = 0.f;
#pragma unroll
    for (int k = 0; k < HH; k += 2) {
      float h0 = readlane_f(hj, k), h1 = readlane_f(hj, k + 1);
      ar0 += h0 * wr[k];     az0 += h0 * wz[k];     an0 += h0 * wn[k];
      ar1 += h1 * wr[k + 1]; az1 += h1 * wz[k + 1]; an1 += h1 * wn[k + 1];
    }
    float r  = sigmoidf_(gir + ar0 + ar1);
    float z  = sigmoidf_(giz + az0 + az1);
    float nn_ = tanhf(gin + r * (an0 + an1));
    hj = (1.f - z) * nn_ + z * hj;
    gir = pir; giz = piz; gin = pin;
    pir = qir; piz = qiz; pin = qin;
  }

  // ---- fused heads: lanes 0..31 = order head, 32..63 = demand head ----
  int half = lane >> 5, jp = lane & 31;
  const float* W1 = half ? dW1 : oW1;
  const float* b1 = half ? db1 : ob1;
  const float* W2 = half ? dW2 : oW2;
  const float* b2 = half ? db2 : ob2;
  float wv[HH];
#pragma unroll
  for (int i = 0; i < HH / 4; ++i)
    *(float4*)&wv[4 * i] = ((const float4*)(W1 + jp * HH))[i];
  float acc = b1[jp];
#pragma unroll
  for (int k = 0; k < HH; ++k)
    acc += readlane_f(hj, k) * wv[k];            // broadcast from own h copy
  float val = fmaxf(acc, 0.f) * W2[jp];
  val += __shfl_down(val, 16, 32);
  val += __shfl_down(val, 8, 32);
  val += __shfl_down(val, 4, 32);
  val += __shfl_down(val, 2, 32);
  val += __shfl_down(val, 1, 32);
  if (jp == 0) out[half * (BB * NN) + seq] = val + b2[0];
}

// ---------------- fallback GRU (R2 design; used if ws too small for gi) -----
__global__ __launch_bounds__(192, 3) void gru_fused_kernel(
    const float* __restrict__ hbuf,
    const float* __restrict__ Wih, const float* __restrict__ Whh,
    const float* __restrict__ bih, const float* __restrict__ bhh,
    const float* __restrict__ oW1, const float* __restrict__ ob1,
    const float* __restrict__ oW2, const float* __restrict__ ob2,
    const float* __restrict__ dW1, const float* __restrict__ db1,
    const float* __restrict__ dW2, const float* __restrict__ db2,
    float* __restrict__ out) {
  __shared__ float gi_sh[SS * 3 * HH];   // 48 KB  [t][gate][j]
  __shared__ float exch[2][3][HH];       // double-buffered gh exchange

  int lane = threadIdx.x & 63;
  int g = (int)threadIdx.x >> 6;
  int seq = blockIdx.x;
  int b = seq >> 7, n = seq & (NN - 1);
  const float* xbase = hbuf + ((size_t)b * SS * NN + (size_t)n) * HH;

  {
    float w[HH];
    const float4* wsrc = (const float4*)(Wih + (size_t)(g * 64 + lane) * HH);
#pragma unroll
    for (int i = 0; i < HH / 4; ++i) *(float4*)&w[4 * i] = wsrc[i];
    float bias = bih[g * 64 + lane];
#pragma unroll 2
    for (int t = 0; t < SS; ++t) {
      const float* xr = xbase + (size_t)t * NN * HH;
      float a0 = bias, a1 = 0.f, a2 = 0.f, a3 = 0.f;
#pragma unroll
      for (int k = 0; k < HH; k += 4) {
        float4 xb = *(const float4*)(xr + k);
        a0 += xb.x * w[k + 0];
        a1 += xb.y * w[k + 1];
        a2 += xb.z * w[k + 2];
        a3 += xb.w * w[k + 3];
      }
      gi_sh[(t * 3 + g) * HH + lane] = (a0 + a1) + (a2 + a3);
    }
  }

  float whh[HH];
  {
    const float4* wsrc = (const float4*)(Whh + (size_t)(g * 64 + lane) * HH);
#pragma unroll
    for (int i = 0; i < HH / 4; ++i) *(float4*)&whh[4 * i] = wsrc[i];
  }
  float bhg = bhh[g * 64 + lane];
  float hj = 0.f;
  __syncthreads();

#pragma unroll 1
  for (int t = 0; t < SS; ++t) {
    float a0 = bhg, a1 = 0.f, a2 = 0.f, a3 = 0.f;
#pragma unroll
    for (int k = 0; k < HH; k += 4) {
      a0 += readlane_f(hj, k + 0) * whh[k + 0];
      a1 += readlane_f(hj, k + 1) * whh[k + 1];
      a2 += readlane_f(hj, k + 2) * whh[k + 2];
      a3 += readlane_f(hj, k + 3) * whh[k + 3];
    }
    float gh = (a0 + a1) + (a2 + a3);
    int slot = t & 1;
    exch[slot][g][lane] = gh;
    __syncthreads();
    float ghr = exch[slot][0][lane];
    float ghz = exch[slot][1][lane];
    float ghn = exch[slot][2][lane];
    float gir = gi_sh[(t * 3 + 0) * HH + lane];
    float giz = gi_sh[(t * 3 + 1) * HH + lane];
    float gin = gi_sh[(t * 3 + 2) * HH + lane];
    float r  = sigmoidf_(gir + ghr);
    float z  = sigmoidf_(giz + ghz);
    float nn_ = tanhf(gin + r * ghn);
    hj = (1.f - z) * nn_ + z * hj;
  }

  if (g == 0) {
    int half = lane >> 5, jp = lane & 31;
    const float* W1 = half ? dW1 : oW1;
    const float* b1 = half ? db1 : ob1;
    const float* W2 = half ? dW2 : oW2;
    const float* b2 = half ? db2 : ob2;
    float wv[HH];
#pragma unroll
    for (int i = 0; i < HH / 4; ++i)
      *(float4*)&wv[4 * i] = ((const float4*)(W1 + jp * HH))[i];
    float acc = b1[jp];
#pragma unroll
    for (int k = 0; k < HH; ++k)
      acc += readlane_f(hj, k) * wv[k];
    float val = fmaxf(acc, 0.f) * W2[jp];
    val += __shfl_down(val, 16, 32);
    val += __shfl_down(val, 8, 32);
    val += __shfl_down(val, 4, 32);
    val += __shfl_down(val, 2, 32);
    val += __shfl_down(val, 1, 32);
    if (jp == 0) out[half * (BB * NN) + seq] = val + b2[0];
  }
}

// ---------------- launch -----------------------------------------------------
extern "C" void kernel_launch(void* const* d_in, const int* in_sizes, int n_in,
                              void* d_out, int out_size, void* d_ws, size_t ws_size,
                              hipStream_t stream) {
  const float* x       = (const float*)d_in[0];
  const int*   ei      = (const int*)d_in[1];
  const float* in_W    = (const float*)d_in[2];
  const float* in_b    = (const float*)d_in[3];
  const float* gat_Wl  = (const float*)d_in[4];
  const float* gat_bl  = (const float*)d_in[5];
  const float* gat_Wr  = (const float*)d_in[6];
  const float* gat_br  = (const float*)d_in[7];
  const float* gat_att = (const float*)d_in[8];
  const float* gat_bias= (const float*)d_in[9];
  const float* gru_Wih = (const float*)d_in[10];
  const float* gru_Whh = (const float*)d_in[11];
  const float* gru_bih = (const float*)d_in[12];
  const float* gru_bhh = (const float*)d_in[13];
  const float* oh_W1   = (const float*)d_in[14];
  const float* oh_b1   = (const float*)d_in[15];
  const float* oh_W2   = (const float*)d_in[16];
  const float* oh_b2   = (const float*)d_in[17];
  const float* dh_W1   = (const float*)d_in[18];
  const float* dh_b1   = (const float*)d_in[19];
  const float* dh_W2   = (const float*)d_in[20];
  const float* dh_b2   = (const float*)d_in[21];
  float* out = (float*)d_out;

  char* ws = (char*)d_ws;
  size_t hfloats = (size_t)BB * SS * NN * HH;           // 8.39M floats
  float* hbuf = (float*)ws;
  size_t off_csr = hfloats * sizeof(float);
  size_t off_buf = off_csr + (160 + 2 * ET) * sizeof(int);
  off_buf = (off_buf + 255) & ~(size_t)255;             // 256B align
  int* csr_off = (int*)(ws + off_csr);
  int* csr_src = csr_off + 160;
  int* csr_tgt = csr_src + ET;
  float* xlbuf = (float*)(ws + off_buf);
  float* xrbuf = xlbuf + hfloats;
  size_t need_gat = off_buf + 2 * hfloats * sizeof(float);
  bool big_gat = (ws_size >= need_gat);
  // gi buffer overlays xl/xr (dead after the GAT layers): RT*192 floats
  float* gibuf = (float*)(ws + off_buf);
  size_t need_gru = off_buf + (size_t)RT * 192 * sizeof(float);  // ~134 MB
  bool big_gru = (ws_size >= need_gru);

  setup_csr_kernel<<<1, 256, 0, stream>>>(ei, csr_off, csr_src, csr_tgt);
  input_proj_kernel<<<(BB * SS * NN) / (4 * 32), 256, 0, stream>>>(x, in_W, in_b, hbuf);
  for (int l = 0; l < LLAYERS; ++l) {
    if (big_gat) {
      xlxr_kernel<<<(BB * SS * NN) / 64, 256, 0, stream>>>(
          hbuf, gat_Wl + l * HH * HH, gat_bl + l * HH,
          gat_Wr + l * HH * HH, gat_br + l * HH, xlbuf, xrbuf);
      gat_edge_kernel<<<BB * SS, 256, 0, stream>>>(
          xlbuf, xrbuf, hbuf, csr_off, csr_src, csr_tgt,
          gat_att + l * HH, gat_bias + l * HH);
    } else {
      gat_fused_kernel<<<BB * SS, 256, 0, stream>>>(
          hbuf, hbuf, csr_off, csr_src, csr_tgt,
          gat_Wl + l * HH * HH, gat_bl + l * HH,
          gat_Wr + l * HH * HH, gat_br + l * HH,
          gat_att + l * HH, gat_bias + l * HH);
    }
  }
  if (big_gru) {
    gi_proj_kernel<<<RT / 64, 192, 0, stream>>>(hbuf, gru_Wih, gru_bih, gibuf);
    gru_rec_kernel<<<BB * NN, 64, 0, stream>>>(
        gibuf, gru_Whh, gru_bhh,
        oh_W1, oh_b1, oh_W2, oh_b2, dh_W1, dh_b1, dh_W2, dh_b2, out);
  } else {
    gru_fused_kernel<<<BB * NN, 192, 0, stream>>>(
        hbuf, gru_Wih, gru_Whh, gru_bih, gru_bhh,
        oh_W1, oh_b1, oh_W2, oh_b2, dh_W1, dh_b1, dh_W2, dh_b2, out);
  }
}